// Round 5
// baseline (551.434 us; speedup 1.0000x reference)
//
#include <hip/hip_runtime.h>

// InteractionBlock: N=50000 nodes, M=32 nbrs, HID=128, FILT=128, NBR=64
//  k1 : per-node fused filter MLP (bf16 MFMA) + filter-weighted neighbor sum -> message (d_out)
//  k2a: u = silu(msg@uw1+ub1) -> bf16 u in d_ws
//  k2b: out = u@uw2+ub2 -> d_out
//
// R4 -> R5 changes (diagnosis: stuck at 2 waves/SIMD (~256 true regs incl.
// accum); all pipes <40% => latency-bound on NT nbr_fea loads + gathers):
//  * software pipeline within the persistent loop, using the 256-reg budget:
//      - next node's nbr_fea (8 NT loads) issued one iteration ahead
//      - next node's nbr_idx prefetched
//      - current node's 16 gather row-loads issued at top of iteration,
//        consumed after GEMM1+silu (~1500cy cover)
//  * GEMM2: w2 LDS read hoisted out of mt loop (halves GEMM2 LDS traffic)
//  * grid 512->256 blocks: 1 resident block/CU; avoids serializing two
//    generations of persistent blocks
//
// MFMA layout conventions (gfx950, 16x16 family, verified m89/m91):
//   A frag (16x16x32): row = lane&15, k = (lane>>4)*8 + j  (short8)
//   A/B frag (16x16x16bf16_1k): row/col = lane&15, k = (lane>>4)*4 + j (short4)
//   C/D: col = lane&15, row = (lane>>4)*4 + reg

#define NN 50000
#define MM 32
#define HID 128
#define NBR 64

typedef __attribute__((ext_vector_type(4))) float f32x4;
typedef __attribute__((ext_vector_type(8))) short s16x8;
typedef __attribute__((ext_vector_type(4))) short s16x4;

__device__ __forceinline__ short f2bf(float x) {
  unsigned u = __builtin_bit_cast(unsigned, x);
  unsigned r = (u + 0x7FFFu + ((u >> 16) & 1u)) >> 16;
  return (short)r;
}

__device__ __forceinline__ float silu(float x) {
  return x / (1.0f + __expf(-x));
}

// sum over the 16 lanes of a row-group (lane&15 varies): rotate-reduce, all VALU
__device__ __forceinline__ float rowsum16(float x) {
  int v = __builtin_bit_cast(int, x);
  v = __builtin_bit_cast(int,
      __builtin_bit_cast(float, v) +
      __builtin_bit_cast(float, __builtin_amdgcn_update_dpp(0, v, 0xB1, 0xF, 0xF, false)));  // xor1
  v = __builtin_bit_cast(int,
      __builtin_bit_cast(float, v) +
      __builtin_bit_cast(float, __builtin_amdgcn_update_dpp(0, v, 0x4E, 0xF, 0xF, false)));  // xor2
  v = __builtin_bit_cast(int,
      __builtin_bit_cast(float, v) +
      __builtin_bit_cast(float, __builtin_amdgcn_update_dpp(0, v, 0x124, 0xF, 0xF, false))); // ror4
  v = __builtin_bit_cast(int,
      __builtin_bit_cast(float, v) +
      __builtin_bit_cast(float, __builtin_amdgcn_update_dpp(0, v, 0x128, 0xF, 0xF, false))); // ror8
  return __builtin_bit_cast(float, v);
}

// ---------------------------------------------------------------- kernel 1
__global__ __launch_bounds__(512, 2) void k_filter_message(
    const float* __restrict__ node_repr, const float* __restrict__ nbr_fea,
    const int* __restrict__ nbr_idx, const float* __restrict__ fw1,
    const float* __restrict__ fb1, const float* __restrict__ fw2,
    const float* __restrict__ fb2, float* __restrict__ msg_out)
{
  // fw1T[f][k]: stride 72 shorts; fw2T[h][k]: stride 136 shorts
  __shared__ __align__(16) short s_w1[128 * 72];      // 18.4 KB
  __shared__ __align__(16) short s_w2[128 * 136];     // 34.8 KB
  __shared__ float s_b1[128];
  __shared__ __align__(16) float s_b2[128];           // read as f32x4

  const int tid = threadIdx.x;
  for (int i = tid; i < 64 * 128; i += 512) {      // fw1 given [k<64][f<128]
    int k = i >> 7, f = i & 127;
    s_w1[f * 72 + k] = f2bf(fw1[i]);
  }
  for (int i = tid; i < 128 * 128; i += 512) {     // fw2 given [k<128][h<128]
    int k = i >> 7, h = i & 127;
    s_w2[h * 136 + k] = f2bf(fw2[i]);
  }
  if (tid < 128) { s_b1[tid] = fb1[tid]; s_b2[tid] = fb2[tid]; }
  __syncthreads();

  const int wave = tid >> 6, lane = tid & 63;
  const int c = lane & 15, g = lane >> 4;
  const int gw = blockIdx.x * 8 + wave;
  const int STRIDE = 256 * 8;   // gridDim.x * waves/block

  // ---- prologue: prefetch node gw's stream data + indices
  f32x4 raw[8];     // nbr_fea rows (f32), [mt*4 + kt*2 + half]
  int idx0, idx1;   // gather rows for current node, m = c and 16+c
  {
    const float* nf = nbr_fea + (size_t)gw * (MM * NBR);
    #pragma unroll
    for (int mt = 0; mt < 2; ++mt)
      #pragma unroll
      for (int kt = 0; kt < 2; ++kt) {
        const f32x4* src = reinterpret_cast<const f32x4*>(
            nf + (mt * 16 + c) * NBR + kt * 32 + g * 8);
        raw[mt * 4 + kt * 2 + 0] = __builtin_nontemporal_load(src);
        raw[mt * 4 + kt * 2 + 1] = __builtin_nontemporal_load(src + 1);
      }
    idx0 = nbr_idx[(size_t)gw * MM + c];
    idx1 = nbr_idx[(size_t)gw * MM + 16 + c];
  }

  for (int n = gw; n < NN; n += STRIDE) {
    int n2 = n + STRIDE; if (n2 >= NN) n2 = n;   // clamped prefetch target

    // 0: issue THIS node's 16 gather loads (consumed in GEMM2, ~1500cy away)
    const float* nrp0 = node_repr + (size_t)idx0 * HID;
    const float* nrp1 = node_repr + (size_t)idx1 * HID;
    f32x4 nr0[8], nr1[8];
    #pragma unroll
    for (int ct = 0; ct < 8; ++ct) {
      nr0[ct] = *reinterpret_cast<const f32x4*>(nrp0 + ct * 16 + 4 * g);
      nr1[ct] = *reinterpret_cast<const f32x4*>(nrp1 + ct * 16 + 4 * g);
    }

    // 1: convert current raws -> B1 frags (waits on prefetched loads)
    s16x8 b1[2][2];
    #pragma unroll
    for (int mt = 0; mt < 2; ++mt)
      #pragma unroll
      for (int kt = 0; kt < 2; ++kt) {
        f32x4 lo = raw[mt * 4 + kt * 2 + 0];
        f32x4 hi = raw[mt * 4 + kt * 2 + 1];
        s16x8 v;
        v[0] = f2bf(lo[0]); v[1] = f2bf(lo[1]); v[2] = f2bf(lo[2]); v[3] = f2bf(lo[3]);
        v[4] = f2bf(hi[0]); v[5] = f2bf(hi[1]); v[6] = f2bf(hi[2]); v[7] = f2bf(hi[3]);
        b1[mt][kt] = v;
      }

    // 2: issue NEXT node's stream loads (consumed next iteration)
    {
      const float* nf2 = nbr_fea + (size_t)n2 * (MM * NBR);
      #pragma unroll
      for (int mt = 0; mt < 2; ++mt)
        #pragma unroll
        for (int kt = 0; kt < 2; ++kt) {
          const f32x4* src = reinterpret_cast<const f32x4*>(
              nf2 + (mt * 16 + c) * NBR + kt * 32 + g * 8);
          raw[mt * 4 + kt * 2 + 0] = __builtin_nontemporal_load(src);
          raw[mt * 4 + kt * 2 + 1] = __builtin_nontemporal_load(src + 1);
        }
    }
    // 3: prefetch NEXT node's indices
    int idx0n = nbr_idx[(size_t)n2 * MM + c];
    int idx1n = nbr_idx[(size_t)n2 * MM + 16 + c];

    // 4: GEMM1 (transposed): h^T[filt][m] = fw1T . nbr^T  (16x16x32)
    //    then bias+silu+pack: P[t][mt] = A-frag of GEMM2 (zero shuffle)
    s16x4 P[8][2];
    #pragma unroll
    for (int t = 0; t < 8; ++t) {
      f32x4 a0 = f32x4{0.f, 0.f, 0.f, 0.f};
      f32x4 a1 = f32x4{0.f, 0.f, 0.f, 0.f};
      #pragma unroll
      for (int kt = 0; kt < 2; ++kt) {
        s16x8 w1f = *reinterpret_cast<const s16x8*>(&s_w1[(t * 16 + c) * 72 + kt * 32 + g * 8]);
        a0 = __builtin_amdgcn_mfma_f32_16x16x32_bf16(w1f, b1[0][kt], a0, 0, 0, 0);
        a1 = __builtin_amdgcn_mfma_f32_16x16x32_bf16(w1f, b1[1][kt], a1, 0, 0, 0);
      }
      s16x4 p0, p1;
      #pragma unroll
      for (int r = 0; r < 4; ++r) {
        float bias = s_b1[t * 16 + g * 4 + r];
        p0[r] = f2bf(silu(a0[r] + bias));
        p1[r] = f2bf(silu(a1[r] + bias));
      }
      P[t][0] = p0;
      P[t][1] = p1;
    }

    // 5: GEMM2 TRANSPOSED (A = w2 frag, B = P; C = filtersT) + fused gather
    //    consume: lane holds filter[m=16mt+c][hid=16ct+4g+r]
    f32x4 pacc[8];
    #pragma unroll
    for (int ct = 0; ct < 8; ++ct) {
      f32x4 t0 = f32x4{0.f, 0.f, 0.f, 0.f};
      f32x4 t1 = f32x4{0.f, 0.f, 0.f, 0.f};
      #pragma unroll
      for (int kt = 0; kt < 8; ++kt) {
        s16x4 w2f = *reinterpret_cast<const s16x4*>(&s_w2[(ct * 16 + c) * 136 + kt * 16 + g * 4]);
        t0 = __builtin_amdgcn_mfma_f32_16x16x16bf16_1k(w2f, P[kt][0], t0, 0, 0, 0);
        t1 = __builtin_amdgcn_mfma_f32_16x16x16bf16_1k(w2f, P[kt][1], t1, 0, 0, 0);
      }
      f32x4 fb = *reinterpret_cast<const f32x4*>(&s_b2[ct * 16 + 4 * g]);
      f32x4 a;
      #pragma unroll
      for (int r = 0; r < 4; ++r)
        a[r] = (t0[r] + fb[r]) * nr0[ct][r] + (t1[r] + fb[r]) * nr1[ct][r];
      pacc[ct] = a;
    }

    // 6: m-sum over the 16 c-lanes (DPP); c==0 stores float4
    #pragma unroll
    for (int ct = 0; ct < 8; ++ct) {
      f32x4 s;
      #pragma unroll
      for (int r = 0; r < 4; ++r) s[r] = rowsum16(pacc[ct][r]);
      if (c == 0)
        *reinterpret_cast<f32x4*>(msg_out + (size_t)n * HID + ct * 16 + 4 * g) = s;
    }

    // 7: rotate prefetched indices
    idx0 = idx0n;
    idx1 = idx1n;
  }
}

// ---------------------------------------------------------------- kernel 2a
// u^T = silu(uw1^T . msg^T + ub1) -> bf16 u[row][128] in ws
__global__ __launch_bounds__(256, 2) void k_update1(
    const float* __restrict__ msg, const float* __restrict__ uw1,
    const float* __restrict__ ub1, short* __restrict__ u_out)
{
  __shared__ __align__(16) short s_w1[128 * 136];   // uw1T[f][k], stride 136
  __shared__ float s_b1[128];
  const int tid = threadIdx.x;
  for (int i = tid; i < 128 * 128; i += 256) {      // uw1 given [k][f]
    int k = i >> 7, f = i & 127;
    s_w1[f * 136 + k] = f2bf(uw1[i]);
  }
  if (tid < 128) s_b1[tid] = ub1[tid];
  __syncthreads();

  const int wave = tid >> 6, lane = tid & 63;
  const int c = lane & 15, g = lane >> 4;
  const long base = (long)(blockIdx.x * 4 + wave) * 32;
  if (base >= NN) return;

  s16x8 bfr[2][4];
  #pragma unroll
  for (int mt = 0; mt < 2; ++mt)
    #pragma unroll
    for (int kt = 0; kt < 4; ++kt) {
      long row = base + mt * 16 + c; if (row > NN - 1) row = NN - 1;
      const float* src = msg + row * HID + kt * 32 + g * 8;
      float4 lo = *reinterpret_cast<const float4*>(src);
      float4 hi = *reinterpret_cast<const float4*>(src + 4);
      s16x8 v;
      v[0] = f2bf(lo.x); v[1] = f2bf(lo.y); v[2] = f2bf(lo.z); v[3] = f2bf(lo.w);
      v[4] = f2bf(hi.x); v[5] = f2bf(hi.y); v[6] = f2bf(hi.z); v[7] = f2bf(hi.w);
      bfr[mt][kt] = v;
    }

  f32x4 acc[8][2];
  #pragma unroll
  for (int t = 0; t < 8; ++t)
    #pragma unroll
    for (int mt = 0; mt < 2; ++mt)
      acc[t][mt] = f32x4{0.f, 0.f, 0.f, 0.f};
  #pragma unroll
  for (int kt = 0; kt < 4; ++kt)
    #pragma unroll
    for (int t = 0; t < 8; ++t) {
      s16x8 a = *reinterpret_cast<const s16x8*>(&s_w1[(t * 16 + c) * 136 + kt * 32 + g * 8]);
      #pragma unroll
      for (int mt = 0; mt < 2; ++mt)
        acc[t][mt] = __builtin_amdgcn_mfma_f32_16x16x32_bf16(a, bfr[mt][kt], acc[t][mt], 0, 0, 0);
    }

  #pragma unroll
  for (int t = 0; t < 8; ++t)
    #pragma unroll
    for (int mt = 0; mt < 2; ++mt) {
      long row = base + mt * 16 + c;
      if (row < NN) {
        s16x4 p;
        #pragma unroll
        for (int r = 0; r < 4; ++r) {
          float x = acc[t][mt][r] + s_b1[t * 16 + g * 4 + r];
          p[r] = f2bf(silu(x));
        }
        *reinterpret_cast<s16x4*>(&u_out[row * HID + t * 16 + g * 4]) = p;
      }
    }
}

// ---------------------------------------------------------------- kernel 2b
// out[m][hid] = u . uw2 + ub2   (16x16x16, A from bf16 u in ws)
__global__ __launch_bounds__(256, 2) void k_update2(
    const short* __restrict__ u, const float* __restrict__ uw2,
    const float* __restrict__ ub2, float* __restrict__ out)
{
  __shared__ __align__(16) short s_w2[128 * 136];   // uw2T[h][k]
  __shared__ float s_b2[128];
  const int tid = threadIdx.x;
  for (int i = tid; i < 128 * 128; i += 256) {      // uw2 given [k][h]
    int k = i >> 7, h = i & 127;
    s_w2[h * 136 + k] = f2bf(uw2[i]);
  }
  if (tid < 128) s_b2[tid] = ub2[tid];
  __syncthreads();

  const int wave = tid >> 6, lane = tid & 63;
  const int c = lane & 15, g = lane >> 4;
  const long base = (long)(blockIdx.x * 4 + wave) * 32;
  if (base >= NN) return;

  s16x4 afr[2][8];
  #pragma unroll
  for (int mt = 0; mt < 2; ++mt)
    #pragma unroll
    for (int kt = 0; kt < 8; ++kt) {
      long row = base + mt * 16 + c; if (row > NN - 1) row = NN - 1;
      afr[mt][kt] = *reinterpret_cast<const s16x4*>(&u[row * HID + kt * 16 + g * 4]);
    }

  f32x4 acc[8][2];
  #pragma unroll
  for (int ct = 0; ct < 8; ++ct)
    #pragma unroll
    for (int mt = 0; mt < 2; ++mt)
      acc[ct][mt] = f32x4{0.f, 0.f, 0.f, 0.f};
  #pragma unroll
  for (int ct = 0; ct < 8; ++ct)
    #pragma unroll
    for (int kt = 0; kt < 8; ++kt) {
      s16x4 b2 = *reinterpret_cast<const s16x4*>(&s_w2[(ct * 16 + c) * 136 + kt * 16 + g * 4]);
      #pragma unroll
      for (int mt = 0; mt < 2; ++mt)
        acc[ct][mt] = __builtin_amdgcn_mfma_f32_16x16x16bf16_1k(afr[mt][kt], b2, acc[ct][mt], 0, 0, 0);
    }

  #pragma unroll
  for (int ct = 0; ct < 8; ++ct) {
    const float bias = s_b2[ct * 16 + c];
    #pragma unroll
    for (int mt = 0; mt < 2; ++mt)
      #pragma unroll
      for (int r = 0; r < 4; ++r) {
        long row = base + mt * 16 + g * 4 + r;
        if (row < NN) out[row * HID + ct * 16 + c] = acc[ct][mt][r] + bias;
      }
  }
}

// ---------------------------------------------------------------- launch
extern "C" void kernel_launch(void* const* d_in, const int* in_sizes, int n_in,
                              void* d_out, int out_size, void* d_ws, size_t ws_size,
                              hipStream_t stream) {
  const float* node_repr = (const float*)d_in[0];
  const float* nbr_fea   = (const float*)d_in[1];
  const int*   nbr_idx   = (const int*)d_in[2];
  const float* fw1 = (const float*)d_in[3];
  const float* fb1 = (const float*)d_in[4];
  const float* fw2 = (const float*)d_in[5];
  const float* fb2 = (const float*)d_in[6];
  const float* uw1 = (const float*)d_in[7];
  const float* ub1 = (const float*)d_in[8];
  const float* uw2 = (const float*)d_in[9];
  const float* ub2 = (const float*)d_in[10];
  float* outp = (float*)d_out;
  short* u_ws = (short*)d_ws;   // bf16 u: NN*128*2B = 12.8 MB

  // k1: 256 blocks x 512 thr (1 resident block/CU, persistent, pipelined)
  k_filter_message<<<256, 512, 0, stream>>>(node_repr, nbr_fea, nbr_idx,
                                            fw1, fb1, fw2, fb2, outp);
  const int rowblocks = (NN + 31) / 32;        // 1563
  const int grid2 = (rowblocks + 3) / 4;       // 391
  k_update1<<<grid2, 256, 0, stream>>>(outp, uw1, ub1, u_ws);
  k_update2<<<grid2, 256, 0, stream>>>(u_ws, uw2, ub2, outp);
}